// Round 1
// baseline (17986.156 us; speedup 1.0000x reference)
//
#include <hip/hip_runtime.h>

#define NB 64
#define NT 1024
#define DIN 12
#define NH 256
#define NG 1024   // 4*H
#define NCLS 17
#define TC 128    // timestep chunk for layer-1 projection
#define NCHUNK 8  // 1024 / 128

__device__ __forceinline__ float sigm(float v) {
    return 1.0f / (1.0f + __expf(-v));
}
__device__ __forceinline__ float tanh_(float v) {
    v = fminf(fmaxf(v, -15.0f), 15.0f);
    float e = __expf(2.0f * v);
    return (e - 1.0f) / (e + 1.0f);
}

// ---------------------------------------------------------------------------
// k_prep: transpose weights for coalesced streaming.
//   WhhT[dir][k][g]  = w_hh[dir][g][k]     (both layers)
//   WihT0[dir][d][g] = w_ih0[dir][g][d]
//   bsum0[dir][g]    = b_ih0 + b_hh0
// ---------------------------------------------------------------------------
__global__ void k_prep(const float* __restrict__ w_hh0, const float* __restrict__ w_hh1,
                       const float* __restrict__ w_ih0,
                       const float* __restrict__ b_ih0, const float* __restrict__ b_hh0,
                       float* __restrict__ WhhT0, float* __restrict__ WhhT1,
                       float* __restrict__ WihT0, float* __restrict__ bsum0) {
    int i = blockIdx.x * 256 + threadIdx.x;   // grid covers 2*256*1024
    if (i < 2 * NH * NG) {
        int g = i & (NG - 1);
        int k = (i >> 10) & (NH - 1);
        int d = i >> 18;
        WhhT0[i] = w_hh0[(d * NG + g) * NH + k];
        WhhT1[i] = w_hh1[(d * NG + g) * NH + k];
    }
    if (i < 2 * DIN * NG) {
        int g  = i & (NG - 1);
        int dd = (i >> 10) % DIN;
        int d  = (i >> 10) / DIN;
        WihT0[i] = w_ih0[(d * NG + g) * DIN + dd];
    }
    if (i < 2 * NG) bsum0[i] = b_ih0[i] + b_hh0[i];
}

// ---------------------------------------------------------------------------
// k_lstm0: layer-0 recurrence, one block per (dir, b). 256 threads.
// Fuses the K=12 input projection (Wih0T in LDS). Streams WhhT0 from L2.
// Thread j computes gates 4j..4j+3 (coalesced float4 weight reads), gates are
// exchanged via LDS so thread j then owns c[j], h[j].
// ---------------------------------------------------------------------------
__launch_bounds__(256)
__global__ void k_lstm0(const float* __restrict__ x, const float* __restrict__ WhhT0,
                        const float* __restrict__ WihT0, const float* __restrict__ bsum0,
                        float* __restrict__ out0) {
    __shared__ float wih[DIN * NG];      // 48 KB  [d][g]
    __shared__ float bsum[NG];           // 4 KB
    __shared__ float hbuf[NH];           // 1 KB
    __shared__ float gbuf[NG];           // 4 KB
    __shared__ float xlds[16];

    const int tid = threadIdx.x;
    const int dir = blockIdx.x >> 6;
    const int b   = blockIdx.x & 63;

    const float* wih_g = WihT0 + dir * DIN * NG;
    const float* bs_g  = bsum0 + dir * NG;
    const float4* wt   = (const float4*)(WhhT0 + dir * NH * NG);  // [k][NG/4 float4]

    for (int i = tid; i < DIN * NG; i += 256) wih[i] = wih_g[i];
    for (int i = tid; i < NG; i += 256) bsum[i] = bs_g[i];
    hbuf[tid] = 0.0f;

    float c = 0.0f, h = 0.0f;
    __syncthreads();

    const float4* wih4 = (const float4*)wih;   // [d][256 float4]
    const float4* bs4  = (const float4*)bsum;

    for (int it = 0; it < NT; ++it) {
        const int t = dir ? (NT - 1 - it) : it;

        hbuf[tid] = h;
        if (tid < 3) ((float4*)xlds)[tid] = ((const float4*)(x + (size_t)(b * NT + t) * DIN))[tid];
        __syncthreads();

        float4 acc = bs4[tid];
        #pragma unroll
        for (int dd = 0; dd < DIN; ++dd) {
            float xv = xlds[dd];
            float4 w = wih4[dd * 256 + tid];
            acc.x += w.x * xv; acc.y += w.y * xv; acc.z += w.z * xv; acc.w += w.w * xv;
        }
        #pragma unroll 2
        for (int k = 0; k < NH; k += 4) {
            float4 h4 = *(const float4*)&hbuf[k];
            float4 w0 = wt[(k + 0) * 256 + tid];
            float4 w1 = wt[(k + 1) * 256 + tid];
            float4 w2 = wt[(k + 2) * 256 + tid];
            float4 w3 = wt[(k + 3) * 256 + tid];
            acc.x += w0.x * h4.x; acc.y += w0.y * h4.x; acc.z += w0.z * h4.x; acc.w += w0.w * h4.x;
            acc.x += w1.x * h4.y; acc.y += w1.y * h4.y; acc.z += w1.z * h4.y; acc.w += w1.w * h4.y;
            acc.x += w2.x * h4.z; acc.y += w2.y * h4.z; acc.z += w2.z * h4.z; acc.w += w2.w * h4.z;
            acc.x += w3.x * h4.w; acc.y += w3.y * h4.w; acc.z += w3.z * h4.w; acc.w += w3.w * h4.w;
        }
        ((float4*)gbuf)[tid] = acc;
        __syncthreads();

        const float gi = gbuf[tid];
        const float gf = gbuf[NH + tid];
        const float gg = gbuf[2 * NH + tid];
        const float go = gbuf[3 * NH + tid];
        c = sigm(gf) * c + sigm(gi) * tanh_(gg);
        h = sigm(go) * tanh_(c);
        out0[(size_t)(b * NT + t) * (2 * NH) + dir * NH + tid] = h;
    }
}

// ---------------------------------------------------------------------------
// k_proj: xp1[dir][b][tl][g] = out0[b][t(tl)][:512] . w_ih1[dir][g][:512] + biases
// fp32 tiled GEMM, 64x64 tile, 256 threads, 4x4 micro-tile, K-step 16.
// For dir==1 the chunk covers descending t so that k_lstm1's step i reads row i.
// ---------------------------------------------------------------------------
#define KT 16
#define LDP 68   // padded row stride (floats) for LDS tiles, float4-aligned

__launch_bounds__(256)
__global__ void k_proj(const float* __restrict__ out0, const float* __restrict__ w_ih1,
                       const float* __restrict__ b_ih1, const float* __restrict__ b_hh1,
                       float* __restrict__ xp1, int chunk) {
    __shared__ float Als[KT * LDP];
    __shared__ float Bls[KT * LDP];

    const int tid = threadIdx.x;
    const int rowbase = blockIdx.x * 64;       // over M = 64*128 rows (b, tl)
    const int colbase = blockIdx.y * 64;       // over N = 1024 gates
    const int dir = blockIdx.z;

    // load assignment: 64 rows x 4 float4-chunks of K
    const int lm = tid >> 2;        // 0..63
    const int kq = tid & 3;         // 0..3

    // A row -> global pointer
    const int r  = rowbase + lm;
    const int ab = r >> 7;          // batch
    const int tl = r & 127;         // local timestep in chunk
    const int t  = dir ? (NT - 1 - chunk * TC - tl) : (chunk * TC + tl);
    const float* arow = out0 + (size_t)(ab * NT + t) * (2 * NH);
    const int gg = colbase + lm;
    const float* brow = w_ih1 + (size_t)(dir * NG + gg) * (2 * NH);

    const int tx = tid & 15;
    const int ty = tid >> 4;

    float acc[4][4];
    #pragma unroll
    for (int q = 0; q < 4; ++q)
        #pragma unroll
        for (int p = 0; p < 4; ++p) acc[q][p] = 0.0f;

    const float4* Als4 = (const float4*)Als;
    const float4* Bls4 = (const float4*)Bls;

    for (int k0 = 0; k0 < 2 * NH; k0 += KT) {
        float4 av = ((const float4*)(arow + k0))[kq];
        float4 bv = ((const float4*)(brow + k0))[kq];
        __syncthreads();
        Als[(kq * 4 + 0) * LDP + lm] = av.x;
        Als[(kq * 4 + 1) * LDP + lm] = av.y;
        Als[(kq * 4 + 2) * LDP + lm] = av.z;
        Als[(kq * 4 + 3) * LDP + lm] = av.w;
        Bls[(kq * 4 + 0) * LDP + lm] = bv.x;
        Bls[(kq * 4 + 1) * LDP + lm] = bv.y;
        Bls[(kq * 4 + 2) * LDP + lm] = bv.z;
        Bls[(kq * 4 + 3) * LDP + lm] = bv.w;
        __syncthreads();
        #pragma unroll
        for (int kk = 0; kk < KT; ++kk) {
            float4 a4 = Als4[kk * (LDP / 4) + ty];
            float4 b4 = Bls4[kk * (LDP / 4) + tx];
            acc[0][0] += a4.x * b4.x; acc[0][1] += a4.x * b4.y; acc[0][2] += a4.x * b4.z; acc[0][3] += a4.x * b4.w;
            acc[1][0] += a4.y * b4.x; acc[1][1] += a4.y * b4.y; acc[1][2] += a4.y * b4.z; acc[1][3] += a4.y * b4.w;
            acc[2][0] += a4.z * b4.x; acc[2][1] += a4.z * b4.y; acc[2][2] += a4.z * b4.z; acc[2][3] += a4.z * b4.w;
            acc[3][0] += a4.w * b4.x; acc[3][1] += a4.w * b4.y; acc[3][2] += a4.w * b4.z; acc[3][3] += a4.w * b4.w;
        }
    }

    // epilogue: add biases, store
    const int col = colbase + tx * 4;
    float4 bias;
    bias.x = b_ih1[dir * NG + col + 0] + b_hh1[dir * NG + col + 0];
    bias.y = b_ih1[dir * NG + col + 1] + b_hh1[dir * NG + col + 1];
    bias.z = b_ih1[dir * NG + col + 2] + b_hh1[dir * NG + col + 2];
    bias.w = b_ih1[dir * NG + col + 3] + b_hh1[dir * NG + col + 3];
    #pragma unroll
    for (int q = 0; q < 4; ++q) {
        const int rr = rowbase + ty * 4 + q;     // (b, tl)
        const int ob = rr >> 7, otl = rr & 127;
        float4 v;
        v.x = acc[q][0] + bias.x;
        v.y = acc[q][1] + bias.y;
        v.z = acc[q][2] + bias.z;
        v.w = acc[q][3] + bias.w;
        *(float4*)(xp1 + ((size_t)((dir * NB + ob) * TC + otl)) * NG + col) = v;
    }
}

// ---------------------------------------------------------------------------
// k_lstm1: layer-1 recurrence over one chunk of TC steps. xproj precomputed.
// Accumulates running sum of h (for mean pooling). State in ws across chunks.
// ---------------------------------------------------------------------------
__launch_bounds__(256)
__global__ void k_lstm1(const float* __restrict__ xp1, const float* __restrict__ WhhT1,
                        float* __restrict__ hstate, float* __restrict__ cstate,
                        float* __restrict__ hsum, int first) {
    __shared__ float hbuf[NH];
    __shared__ float gbuf[NG];

    const int tid = threadIdx.x;
    const int dir = blockIdx.x >> 6;
    const int b   = blockIdx.x & 63;
    const int sidx = (dir * NB + b) * NH + tid;

    float h, c, sum;
    if (first) { h = 0.0f; c = 0.0f; sum = 0.0f; }
    else { h = hstate[sidx]; c = cstate[sidx]; sum = hsum[sidx]; }

    const float4* wt = (const float4*)(WhhT1 + dir * NH * NG);
    const float4* xp = (const float4*)(xp1 + (size_t)(dir * NB + b) * TC * NG);

    for (int it = 0; it < TC; ++it) {
        hbuf[tid] = h;
        __syncthreads();

        float4 acc = xp[it * 256 + tid];
        #pragma unroll 2
        for (int k = 0; k < NH; k += 4) {
            float4 h4 = *(const float4*)&hbuf[k];
            float4 w0 = wt[(k + 0) * 256 + tid];
            float4 w1 = wt[(k + 1) * 256 + tid];
            float4 w2 = wt[(k + 2) * 256 + tid];
            float4 w3 = wt[(k + 3) * 256 + tid];
            acc.x += w0.x * h4.x; acc.y += w0.y * h4.x; acc.z += w0.z * h4.x; acc.w += w0.w * h4.x;
            acc.x += w1.x * h4.y; acc.y += w1.y * h4.y; acc.z += w1.z * h4.y; acc.w += w1.w * h4.y;
            acc.x += w2.x * h4.z; acc.y += w2.y * h4.z; acc.z += w2.z * h4.z; acc.w += w2.w * h4.z;
            acc.x += w3.x * h4.w; acc.y += w3.y * h4.w; acc.z += w3.z * h4.w; acc.w += w3.w * h4.w;
        }
        ((float4*)gbuf)[tid] = acc;
        __syncthreads();

        const float gi = gbuf[tid];
        const float gf = gbuf[NH + tid];
        const float gg = gbuf[2 * NH + tid];
        const float go = gbuf[3 * NH + tid];
        c = sigm(gf) * c + sigm(gi) * tanh_(gg);
        h = sigm(go) * tanh_(c);
        sum += h;
    }
    hstate[sidx] = h;
    cstate[sidx] = c;
    hsum[sidx]   = sum;
}

// ---------------------------------------------------------------------------
// k_fc: out[b][n] = fc_b[n] + sum_k (hsum[k]/T) * fc_w[n][k]
// ---------------------------------------------------------------------------
__global__ void k_fc(const float* __restrict__ hsum, const float* __restrict__ fc_w,
                     const float* __restrict__ fc_b, float* __restrict__ out) {
    const int b = blockIdx.x;
    const int n = threadIdx.x;
    if (n >= NCLS) return;
    float acc = fc_b[n];
    const float inv = 1.0f / (float)NT;
    for (int k = 0; k < 2 * NH; ++k) {
        float p = hsum[((k >> 8) * NB + b) * NH + (k & 255)];
        acc += (p * inv) * fc_w[n * 2 * NH + k];
    }
    out[b * NCLS + n] = acc;
}

// ---------------------------------------------------------------------------
extern "C" void kernel_launch(void* const* d_in, const int* in_sizes, int n_in,
                              void* d_out, int out_size, void* d_ws, size_t ws_size,
                              hipStream_t stream) {
    const float* x     = (const float*)d_in[0];
    const float* w_ih0 = (const float*)d_in[1];
    const float* w_hh0 = (const float*)d_in[2];
    const float* b_ih0 = (const float*)d_in[3];
    const float* b_hh0 = (const float*)d_in[4];
    const float* w_ih1 = (const float*)d_in[5];
    const float* w_hh1 = (const float*)d_in[6];
    const float* b_ih1 = (const float*)d_in[7];
    const float* b_hh1 = (const float*)d_in[8];
    const float* fc_w  = (const float*)d_in[9];
    const float* fc_b  = (const float*)d_in[10];
    float* out = (float*)d_out;

    float* ws = (float*)d_ws;
    float* WhhT0  = ws;                              // [2][256][1024]
    float* WhhT1  = WhhT0 + 2 * NH * NG;             // [2][256][1024]
    float* WihT0  = WhhT1 + 2 * NH * NG;             // [2][12][1024]
    float* bsum0  = WihT0 + 2 * DIN * NG;            // [2][1024]
    float* out0   = bsum0 + 2 * NG;                  // [64][1024][512]
    float* xp1    = out0 + (size_t)NB * NT * 2 * NH; // [2][64][128][1024]
    float* hstate = xp1 + (size_t)2 * NB * TC * NG;  // [2][64][256]
    float* cstate = hstate + 2 * NB * NH;
    float* hsum   = cstate + 2 * NB * NH;

    hipLaunchKernelGGL(k_prep, dim3(2048), dim3(256), 0, stream,
                       w_hh0, w_hh1, w_ih0, b_ih0, b_hh0, WhhT0, WhhT1, WihT0, bsum0);

    hipLaunchKernelGGL(k_lstm0, dim3(128), dim3(256), 0, stream,
                       x, WhhT0, WihT0, bsum0, out0);

    for (int c = 0; c < NCHUNK; ++c) {
        hipLaunchKernelGGL(k_proj, dim3(128, 16, 2), dim3(256), 0, stream,
                           out0, w_ih1, b_ih1, b_hh1, xp1, c);
        hipLaunchKernelGGL(k_lstm1, dim3(128), dim3(256), 0, stream,
                           xp1, WhhT1, hstate, cstate, hsum, (c == 0) ? 1 : 0);
    }

    hipLaunchKernelGGL(k_fc, dim3(64), dim3(32), 0, stream, hsum, fc_w, fc_b, out);
}